// Round 1
// baseline (872.462 us; speedup 1.0000x reference)
//
#include <hip/hip_runtime.h>
#include <math.h>

// Problem constants (fixed by the reference)
#define BATCH   131072
#define KTOT    512        // D
#define NCOL    64         // S*P
#define THREADS 256
#define BM      256        // rows per block
#define KT      16         // k-tile

// LDS layout (floats)
#define FT_PITCH 260                     // padded row length for transposed feature tile
#define FT_BUF   (KT * FT_PITCH)         // 4160
#define WT_OFF   (2 * FT_BUF)            // 8320
#define WT_BUF   (KT * NCOL)             // 1024
#define ENC0_OFF (WT_OFF + 2 * WT_BUF)   // 10368
#define SMEM_FLOATS (ENC0_OFF + BM * 4)  // 11392 floats = 45568 B

// epilogue weight overlay (re-uses dead ft buf0 region after the K loop)
#define MF_OFF 0
#define W1_OFF 128
#define B1_OFF 2176
#define W2_OFF 2240
#define B2_OFF 2304

__global__ __launch_bounds__(THREADS, 2)
void mps_fused(const float* __restrict__ feat, const float* __restrict__ encW,
               const float* __restrict__ encB, const float* __restrict__ lng,
               const float* __restrict__ lnb,  const float* __restrict__ mf,
               const float* __restrict__ W1,   const float* __restrict__ b1,
               const float* __restrict__ W2,   const float* __restrict__ b2,
               float* __restrict__ out)
{
    __shared__ float smem[SMEM_FLOATS];
    const int t  = threadIdx.x;
    const int tr = t >> 3;          // 0..31 : row-group (8 rows each)
    const int tc = t & 7;           // 0..7  : col-group (8 cols each)
    const long r0 = (long)blockIdx.x * BM;

    // per-thread encoder bias for its 8 columns
    float eb[8];
    {
        float4 e0 = *(const float4*)(encB + tc * 8);
        float4 e1 = *(const float4*)(encB + tc * 8 + 4);
        eb[0]=e0.x; eb[1]=e0.y; eb[2]=e0.z; eb[3]=e0.w;
        eb[4]=e1.x; eb[5]=e1.y; eb[6]=e1.z; eb[7]=e1.w;
    }

    float acc[8][8];
    #pragma unroll
    for (int i = 0; i < 8; ++i)
        #pragma unroll
        for (int j = 0; j < 8; ++j) acc[i][j] = 0.f;

    // staging roles
    const int fr = t >> 2;          // 0..63 feature row within quarter
    const int fk = (t & 3) * 4;     // 0..12 k offset (float4)
    const int wk = t >> 4;          // 0..15 W k row
    const int wc = (t & 15) * 4;    // 0..60 W col (float4)

    float4 fld[4];
    float4 wld;

    // ---------------- prologue: load + write k-step 0 ----------------
    #pragma unroll
    for (int q = 0; q < 4; ++q)
        fld[q] = *(const float4*)(feat + (r0 + fr + 64 * q) * KTOT + fk);
    wld = *(const float4*)(encW + (long)wk * NCOL + wc);

    {
        float* fb = smem;  // buf 0
        #pragma unroll
        for (int q = 0; q < 4; ++q) {
            const float v[4] = {fld[q].x, fld[q].y, fld[q].z, fld[q].w};
            #pragma unroll
            for (int j = 0; j < 4; ++j)
                fb[(fk + j) * FT_PITCH + fr + 64 * q] = v[j];
        }
        *(float4*)(smem + WT_OFF + wk * NCOL + wc) = wld;
    }
    __syncthreads();

    // ---------------- K loop: double-buffered, 32 steps ----------------
    const int NSTEP = KTOT / KT;   // 32
    for (int s = 0; s < NSTEP; ++s) {
        const int cur = s & 1;
        if (s + 1 < NSTEP) {
            const int k0 = (s + 1) * KT;
            #pragma unroll
            for (int q = 0; q < 4; ++q)
                fld[q] = *(const float4*)(feat + (r0 + fr + 64 * q) * KTOT + k0 + fk);
            wld = *(const float4*)(encW + (long)(k0 + wk) * NCOL + wc);
        }
        const float* fb = smem + cur * FT_BUF;
        const float* wb = smem + WT_OFF + cur * WT_BUF;
        #pragma unroll
        for (int kk = 0; kk < KT; ++kk) {
            float4 f0 = *(const float4*)(fb + kk * FT_PITCH + tr * 8);
            float4 f1 = *(const float4*)(fb + kk * FT_PITCH + tr * 8 + 4);
            float4 w0 = *(const float4*)(wb + kk * NCOL + tc * 8);
            float4 w1 = *(const float4*)(wb + kk * NCOL + tc * 8 + 4);
            const float fv[8] = {f0.x,f0.y,f0.z,f0.w,f1.x,f1.y,f1.z,f1.w};
            const float wv[8] = {w0.x,w0.y,w0.z,w0.w,w1.x,w1.y,w1.z,w1.w};
            #pragma unroll
            for (int i = 0; i < 8; ++i)
                #pragma unroll
                for (int j = 0; j < 8; ++j)
                    acc[i][j] = fmaf(fv[i], wv[j], acc[i][j]);
        }
        if (s + 1 < NSTEP) {
            const int nxt = 1 - cur;
            float* fbn = smem + nxt * FT_BUF;
            #pragma unroll
            for (int q = 0; q < 4; ++q) {
                const float v[4] = {fld[q].x, fld[q].y, fld[q].z, fld[q].w};
                #pragma unroll
                for (int j = 0; j < 4; ++j)
                    fbn[(fk + j) * FT_PITCH + fr + 64 * q] = v[j];
            }
            *(float4*)(smem + WT_OFF + nxt * WT_BUF + wk * NCOL + wc) = wld;
        }
        __syncthreads();
    }

    // ---------------- bias + relu + LayerNorm stats ----------------
    float sr[8], qr[8];
    #pragma unroll
    for (int i = 0; i < 8; ++i) {
        float ss = 0.f, qq = 0.f;
        #pragma unroll
        for (int j = 0; j < 8; ++j) {
            float a = acc[i][j] + eb[j];
            a = a > 0.f ? a : 0.f;
            acc[i][j] = a;
            ss += a;
            qq = fmaf(a, a, qq);
        }
        sr[i] = ss; qr[i] = qq;
    }
    #pragma unroll
    for (int d = 1; d < 8; d <<= 1) {
        #pragma unroll
        for (int i = 0; i < 8; ++i) {
            sr[i] += __shfl_xor(sr[i], d, 64);
            qr[i] += __shfl_xor(qr[i], d, 64);
        }
    }

    if (tc == 0) {
        // this thread holds cols 0..7 -> cols 0..3 are site-0 phys dims
        float4 g4 = *(const float4*)lng;
        float4 b4 = *(const float4*)lnb;
        #pragma unroll
        for (int i = 0; i < 8; ++i) {
            float mu  = sr[i] * (1.f / 64.f);
            float var = qr[i] * (1.f / 64.f) - mu * mu;
            float rs  = rsqrtf(var + 1e-5f);
            float4 e;
            e.x = (acc[i][0] - mu) * rs * g4.x + b4.x;
            e.y = (acc[i][1] - mu) * rs * g4.y + b4.y;
            e.z = (acc[i][2] - mu) * rs * g4.z + b4.z;
            e.w = (acc[i][3] - mu) * rs * g4.w + b4.w;
            *(float4*)(smem + ENC0_OFF + (tr * 8 + i) * 4) = e;
        }
    }

    // overlay epilogue weights into the (now dead) ft buf0 region
    for (int idx = t; idx < 128; idx += THREADS)  smem[MF_OFF + idx] = mf[idx];
    for (int idx = t; idx < 2048; idx += THREADS) smem[W1_OFF + idx] = W1[idx];
    if (t < 64)                    smem[B1_OFF + t]        = b1[t];
    else if (t < 128)              smem[W2_OFF + (t - 64)] = W2[t - 64];
    else if (t == 128)             smem[B2_OFF]            = b2[0];
    __syncthreads();

    // ---------------- fused MPS site-0 + decoder, 1 row per thread ----------------
    float ev[4];
    {
        float4 e = *(const float4*)(smem + ENC0_OFF + t * 4);
        ev[0] = e.x; ev[1] = e.y; ev[2] = e.z; ev[3] = e.w;
    }

    float cs[32];
    #pragma unroll
    for (int x = 0; x < 32; ++x) cs[x] = 0.f;
    #pragma unroll
    for (int p = 0; p < 4; ++p) {
        const float ep = ev[p];
        #pragma unroll
        for (int xq = 0; xq < 8; ++xq) {
            float4 w = *(const float4*)(smem + MF_OFF + p * 32 + xq * 4);
            cs[xq*4+0] = fmaf(ep, w.x, cs[xq*4+0]);
            cs[xq*4+1] = fmaf(ep, w.y, cs[xq*4+1]);
            cs[xq*4+2] = fmaf(ep, w.z, cs[xq*4+2]);
            cs[xq*4+3] = fmaf(ep, w.w, cs[xq*4+3]);
        }
    }

    float dv[64];
    #pragma unroll
    for (int j = 0; j < 64; ++j) dv[j] = 0.f;
    #pragma unroll
    for (int x = 0; x < 32; ++x) {
        const float c = cs[x];
        #pragma unroll
        for (int jq = 0; jq < 16; ++jq) {
            float4 w = *(const float4*)(smem + W1_OFF + x * 64 + jq * 4);
            dv[jq*4+0] = fmaf(c, w.x, dv[jq*4+0]);
            dv[jq*4+1] = fmaf(c, w.y, dv[jq*4+1]);
            dv[jq*4+2] = fmaf(c, w.z, dv[jq*4+2]);
            dv[jq*4+3] = fmaf(c, w.w, dv[jq*4+3]);
        }
    }

    float z = 0.f;
    #pragma unroll
    for (int jq = 0; jq < 16; ++jq) {
        float4 bb = *(const float4*)(smem + B1_OFF + jq * 4);
        float4 ww = *(const float4*)(smem + W2_OFF + jq * 4);
        float a0 = dv[jq*4+0] + bb.x; a0 = a0 > 0.f ? a0 : 0.f; z = fmaf(a0, ww.x, z);
        float a1 = dv[jq*4+1] + bb.y; a1 = a1 > 0.f ? a1 : 0.f; z = fmaf(a1, ww.y, z);
        float a2 = dv[jq*4+2] + bb.z; a2 = a2 > 0.f ? a2 : 0.f; z = fmaf(a2, ww.z, z);
        float a3 = dv[jq*4+3] + bb.w; a3 = a3 > 0.f ? a3 : 0.f; z = fmaf(a3, ww.w, z);
    }
    z += smem[B2_OFF];
    out[r0 + t] = 1.f / (1.f + expf(-z));
}

extern "C" void kernel_launch(void* const* d_in, const int* in_sizes, int n_in,
                              void* d_out, int out_size, void* d_ws, size_t ws_size,
                              hipStream_t stream)
{
    const float* feat = (const float*)d_in[0];   // [B,512]
    const float* encW = (const float*)d_in[1];   // [512,64]
    const float* encB = (const float*)d_in[2];   // [64]
    const float* lng  = (const float*)d_in[3];   // [64] (only 0..3 used)
    const float* lnb  = (const float*)d_in[4];   // [64] (only 0..3 used)
    const float* mf   = (const float*)d_in[5];   // [4,32]
    // d_in[6] = mps_mid, d_in[7] = mps_last : dead code in the reference
    const float* W1   = (const float*)d_in[8];   // [32,64]
    const float* b1   = (const float*)d_in[9];   // [64]
    const float* W2   = (const float*)d_in[10];  // [64,1]
    const float* b2   = (const float*)d_in[11];  // [1]
    float* out = (float*)d_out;

    dim3 grid(BATCH / BM), block(THREADS);
    hipLaunchKernelGGL(mps_fused, grid, block, 0, stream,
                       feat, encW, encB, lng, lnb, mf, W1, b1, W2, b2, out);
}

// Round 2
// 844.779 us; speedup vs baseline: 1.0328x; 1.0328x over previous
//
#include <hip/hip_runtime.h>
#include <math.h>

// Problem constants (fixed by the reference)
#define BATCH   131072
#define KTOT    512        // D
#define NCOL    64         // S*P
#define THREADS 256
#define BM      256        // rows per block
#define KT      16         // k-tile

// ---------------- LDS layout (floats) ----------------
// Main-loop regions:
#define FT_PITCH 260                     // padded row length, transposed feature tile
#define FT_BUF   (KT * FT_PITCH)         // 4160
#define WT_OFF   (2 * FT_BUF)            // 8320
#define WT_BUF   (KT * NCOL)             // 1024
// Epilogue overlays (ft/wt regions are dead after the K loop):
#define CS_OFF   0                       // cs^T [32][CS_PITCH], over ft bufs
#define CS_PITCH 260                     // 32*260 = 8320 floats
#define MF_OFF   8320                    // mps_first [4][32] = 128
#define W1_OFF   8448                    // dec_W1 [32][64] = 2048
#define B1_OFF   10496                   // 64
#define W2_OFF   10560                   // 64
#define B2_OFF   10624                   // 1
#define ENC0_OFF 10628                   // [256][4] = 1024 (disjoint from overlays)
#define SMEM_FLOATS (ENC0_OFF + BM * 4)  // 11652 floats = 46608 B

__global__ __launch_bounds__(THREADS, 2)
void mps_fused(const float* __restrict__ feat, const float* __restrict__ encW,
               const float* __restrict__ encB, const float* __restrict__ lng,
               const float* __restrict__ lnb,  const float* __restrict__ mf,
               const float* __restrict__ W1,   const float* __restrict__ b1,
               const float* __restrict__ W2,   const float* __restrict__ b2,
               float* __restrict__ out)
{
    __shared__ float smem[SMEM_FLOATS];
    const int t  = threadIdx.x;
    const int tr = t >> 3;          // 0..31 : row-group (8 rows each)
    const int tc = t & 7;           // 0..7  : col-group (8 cols each)
    const long r0 = (long)blockIdx.x * BM;

    float acc[8][8];
    #pragma unroll
    for (int i = 0; i < 8; ++i)
        #pragma unroll
        for (int j = 0; j < 8; ++j) acc[i][j] = 0.f;

    // staging roles
    const int fr = t >> 2;          // 0..63 feature row within quarter
    const int fk = (t & 3) * 4;     // 0..12 k offset (float4)
    const int wk = t >> 4;          // 0..15 W k row
    const int wc = (t & 15) * 4;    // 0..60 W col (float4)

    float4 fld[4];
    float4 wld;

    // ---------------- prologue: load + write k-step 0 ----------------
    #pragma unroll
    for (int q = 0; q < 4; ++q)
        fld[q] = *(const float4*)(feat + (r0 + fr + 64 * q) * KTOT + fk);
    wld = *(const float4*)(encW + (long)wk * NCOL + wc);

    {
        float* fb = smem;  // buf 0
        #pragma unroll
        for (int q = 0; q < 4; ++q) {
            const float v[4] = {fld[q].x, fld[q].y, fld[q].z, fld[q].w};
            #pragma unroll
            for (int j = 0; j < 4; ++j)
                fb[(fk + j) * FT_PITCH + fr + 64 * q] = v[j];
        }
        *(float4*)(smem + WT_OFF + wk * NCOL + wc) = wld;
    }
    __syncthreads();

    // ---------------- K loop: double-buffered, 32 steps ----------------
    const int NSTEP = KTOT / KT;   // 32
    for (int s = 0; s < NSTEP; ++s) {
        const int cur = s & 1;
        if (s + 1 < NSTEP) {
            const int k0 = (s + 1) * KT;
            #pragma unroll
            for (int q = 0; q < 4; ++q)
                fld[q] = *(const float4*)(feat + (r0 + fr + 64 * q) * KTOT + k0 + fk);
            wld = *(const float4*)(encW + (long)(k0 + wk) * NCOL + wc);
        }
        const float* fb = smem + cur * FT_BUF;
        const float* wb = smem + WT_OFF + cur * WT_BUF;
        #pragma unroll
        for (int kk = 0; kk < KT; ++kk) {
            float4 f0 = *(const float4*)(fb + kk * FT_PITCH + tr * 8);
            float4 f1 = *(const float4*)(fb + kk * FT_PITCH + tr * 8 + 4);
            float4 w0 = *(const float4*)(wb + kk * NCOL + tc * 8);
            float4 w1 = *(const float4*)(wb + kk * NCOL + tc * 8 + 4);
            const float fv[8] = {f0.x,f0.y,f0.z,f0.w,f1.x,f1.y,f1.z,f1.w};
            const float wv[8] = {w0.x,w0.y,w0.z,w0.w,w1.x,w1.y,w1.z,w1.w};
            #pragma unroll
            for (int i = 0; i < 8; ++i)
                #pragma unroll
                for (int j = 0; j < 8; ++j)
                    acc[i][j] = fmaf(fv[i], wv[j], acc[i][j]);
        }
        if (s + 1 < NSTEP) {
            const int nxt = 1 - cur;
            float* fbn = smem + nxt * FT_BUF;
            #pragma unroll
            for (int q = 0; q < 4; ++q) {
                const float v[4] = {fld[q].x, fld[q].y, fld[q].z, fld[q].w};
                #pragma unroll
                for (int j = 0; j < 4; ++j)
                    fbn[(fk + j) * FT_PITCH + fr + 64 * q] = v[j];
            }
            *(float4*)(smem + WT_OFF + nxt * WT_BUF + wk * NCOL + wc) = wld;
        }
        __syncthreads();
    }

    // ---------------- bias + relu + LayerNorm stats ----------------
    float eb[8];
    {
        float4 e0 = *(const float4*)(encB + tc * 8);
        float4 e1 = *(const float4*)(encB + tc * 8 + 4);
        eb[0]=e0.x; eb[1]=e0.y; eb[2]=e0.z; eb[3]=e0.w;
        eb[4]=e1.x; eb[5]=e1.y; eb[6]=e1.z; eb[7]=e1.w;
    }
    float sr[8], qr[8];
    #pragma unroll
    for (int i = 0; i < 8; ++i) {
        float ss = 0.f, qq = 0.f;
        #pragma unroll
        for (int j = 0; j < 8; ++j) {
            float a = acc[i][j] + eb[j];
            a = a > 0.f ? a : 0.f;
            acc[i][j] = a;
            ss += a;
            qq = fmaf(a, a, qq);
        }
        sr[i] = ss; qr[i] = qq;
    }
    #pragma unroll
    for (int d = 1; d < 8; d <<= 1) {
        #pragma unroll
        for (int i = 0; i < 8; ++i) {
            sr[i] += __shfl_xor(sr[i], d, 64);
            qr[i] += __shfl_xor(qr[i], d, 64);
        }
    }

    if (tc == 0) {
        // this thread holds cols 0..7 -> cols 0..3 are site-0 phys dims
        float4 g4 = *(const float4*)lng;
        float4 b4 = *(const float4*)lnb;
        #pragma unroll
        for (int i = 0; i < 8; ++i) {
            float mu  = sr[i] * (1.f / 64.f);
            float var = qr[i] * (1.f / 64.f) - mu * mu;
            float rs  = rsqrtf(var + 1e-5f);
            float4 e;
            e.x = (acc[i][0] - mu) * rs * g4.x + b4.x;
            e.y = (acc[i][1] - mu) * rs * g4.y + b4.y;
            e.z = (acc[i][2] - mu) * rs * g4.z + b4.z;
            e.w = (acc[i][3] - mu) * rs * g4.w + b4.w;
            *(float4*)(smem + ENC0_OFF + (tr * 8 + i) * 4) = e;
        }
    }

    // overlay epilogue weights into the (now dead) wt region
    for (int idx = t; idx < 128; idx += THREADS)  smem[MF_OFF + idx] = mf[idx];
    for (int idx = t; idx < 2048; idx += THREADS) smem[W1_OFF + idx] = W1[idx];
    if (t < 64)                    smem[B1_OFF + t]        = b1[t];
    else if (t < 128)              smem[W2_OFF + (t - 64)] = W2[t - 64];
    else if (t == 128)             smem[B2_OFF]            = b2[0];
    __syncthreads();

    // ---------------- MPS site-0: cs^T[32][256] into LDS (1 row/thread) ----------------
    {
        float4 e = *(const float4*)(smem + ENC0_OFF + t * 4);
        float cs[32];
        #pragma unroll
        for (int xq = 0; xq < 8; ++xq) {
            float4 m0 = *(const float4*)(smem + MF_OFF + 0 * 32 + xq * 4);
            float4 m1 = *(const float4*)(smem + MF_OFF + 1 * 32 + xq * 4);
            float4 m2 = *(const float4*)(smem + MF_OFF + 2 * 32 + xq * 4);
            float4 m3 = *(const float4*)(smem + MF_OFF + 3 * 32 + xq * 4);
            cs[xq*4+0] = fmaf(e.x, m0.x, fmaf(e.y, m1.x, fmaf(e.z, m2.x, e.w * m3.x)));
            cs[xq*4+1] = fmaf(e.x, m0.y, fmaf(e.y, m1.y, fmaf(e.z, m2.y, e.w * m3.y)));
            cs[xq*4+2] = fmaf(e.x, m0.z, fmaf(e.y, m1.z, fmaf(e.z, m2.z, e.w * m3.z)));
            cs[xq*4+3] = fmaf(e.x, m0.w, fmaf(e.y, m1.w, fmaf(e.z, m2.w, e.w * m3.w)));
        }
        #pragma unroll
        for (int x = 0; x < 32; ++x)
            smem[CS_OFF + x * CS_PITCH + t] = cs[x];   // banks: (x*4 + t) % 32 -> 2 lanes/bank, free
    }
    __syncthreads();

    // ---------------- decoder GEMM: C2[256][64] = cs_mat[256][32] @ W1[32][64] ----------------
    #pragma unroll
    for (int i = 0; i < 8; ++i)
        #pragma unroll
        for (int j = 0; j < 8; ++j) acc[i][j] = 0.f;

    #pragma unroll 8
    for (int kk = 0; kk < 32; ++kk) {
        float4 f0 = *(const float4*)(smem + CS_OFF + kk * CS_PITCH + tr * 8);
        float4 f1 = *(const float4*)(smem + CS_OFF + kk * CS_PITCH + tr * 8 + 4);
        float4 w0 = *(const float4*)(smem + W1_OFF + kk * NCOL + tc * 8);
        float4 w1 = *(const float4*)(smem + W1_OFF + kk * NCOL + tc * 8 + 4);
        const float fv[8] = {f0.x,f0.y,f0.z,f0.w,f1.x,f1.y,f1.z,f1.w};
        const float wv[8] = {w0.x,w0.y,w0.z,w0.w,w1.x,w1.y,w1.z,w1.w};
        #pragma unroll
        for (int i = 0; i < 8; ++i)
            #pragma unroll
            for (int j = 0; j < 8; ++j)
                acc[i][j] = fmaf(fv[i], wv[j], acc[i][j]);
    }

    // ---------------- bias + relu + dot(W2) + 8-lane reduce + sigmoid ----------------
    {
        float4 bb0 = *(const float4*)(smem + B1_OFF + tc * 8);
        float4 bb1 = *(const float4*)(smem + B1_OFF + tc * 8 + 4);
        float4 ww0 = *(const float4*)(smem + W2_OFF + tc * 8);
        float4 ww1 = *(const float4*)(smem + W2_OFF + tc * 8 + 4);
        const float bv[8] = {bb0.x,bb0.y,bb0.z,bb0.w,bb1.x,bb1.y,bb1.z,bb1.w};
        const float wv[8] = {ww0.x,ww0.y,ww0.z,ww0.w,ww1.x,ww1.y,ww1.z,ww1.w};
        const float b2v = smem[B2_OFF];
        #pragma unroll
        for (int i = 0; i < 8; ++i) {
            float z = 0.f;
            #pragma unroll
            for (int j = 0; j < 8; ++j) {
                float a = acc[i][j] + bv[j];
                a = a > 0.f ? a : 0.f;
                z = fmaf(a, wv[j], z);
            }
            #pragma unroll
            for (int d = 1; d < 8; d <<= 1)
                z += __shfl_xor(z, d, 64);
            if (tc == 0)
                out[r0 + tr * 8 + i] = 1.f / (1.f + expf(-(z + b2v)));
        }
    }
}

extern "C" void kernel_launch(void* const* d_in, const int* in_sizes, int n_in,
                              void* d_out, int out_size, void* d_ws, size_t ws_size,
                              hipStream_t stream)
{
    const float* feat = (const float*)d_in[0];   // [B,512]
    const float* encW = (const float*)d_in[1];   // [512,64]
    const float* encB = (const float*)d_in[2];   // [64]
    const float* lng  = (const float*)d_in[3];   // [64] (only 0..3 used)
    const float* lnb  = (const float*)d_in[4];   // [64] (only 0..3 used)
    const float* mf   = (const float*)d_in[5];   // [4,32]
    // d_in[6] = mps_mid, d_in[7] = mps_last : dead code in the reference
    const float* W1   = (const float*)d_in[8];   // [32,64]
    const float* b1   = (const float*)d_in[9];   // [64]
    const float* W2   = (const float*)d_in[10];  // [64,1]
    const float* b2   = (const float*)d_in[11];  // [1]
    float* out = (float*)d_out;

    dim3 grid(BATCH / BM), block(THREADS);
    hipLaunchKernelGGL(mps_fused, grid, block, 0, stream,
                       feat, encW, encB, lng, lnb, mf, W1, b1, W2, b2, out);
}

// Round 3
// 681.320 us; speedup vs baseline: 1.2805x; 1.2399x over previous
//
#include <hip/hip_runtime.h>
#include <math.h>

// Problem constants (fixed by the reference)
#define BATCH   131072
#define KTOT    512        // D
#define NCOL    64         // S*P
#define THREADS 256
#define BM      256        // rows per block
#define KT      16         // k-tile
#define NSTEP   (KTOT / KT)

// ---------------- LDS layout (floats) ----------------
#define FT_PITCH 260                     // padded row length, transposed feature tile
#define FT_BUF   (KT * FT_PITCH)         // 4160
#define WT_OFF   (2 * FT_BUF)            // 8320
#define WT_BUF   (KT * NCOL)             // 1024
// Epilogue overlays (ft/wt regions dead after the K loop):
#define CS_OFF   0                       // cs^T [32][CS_PITCH] over ft bufs
#define CS_PITCH 260
#define MF_OFF   8320                    // mps_first [4][32]
#define W1_OFF   8448                    // dec_W1 [32][64]
#define B1_OFF   10496
#define W2_OFF   10560
#define B2_OFF   10624
#define ENC0_OFF 10628                   // [256][4]
#define SMEM_FLOATS (ENC0_OFF + BM * 4)  // 11652 floats

// ---- inner-product body: NO arrays, named scalars only (anti-scratch) ----
#define FMA8(a0, a1, fs) do { \
    a0.x = fmaf(fs, w0.x, a0.x); a0.y = fmaf(fs, w0.y, a0.y); \
    a0.z = fmaf(fs, w0.z, a0.z); a0.w = fmaf(fs, w0.w, a0.w); \
    a1.x = fmaf(fs, w1.x, a1.x); a1.y = fmaf(fs, w1.y, a1.y); \
    a1.z = fmaf(fs, w1.z, a1.z); a1.w = fmaf(fs, w1.w, a1.w); \
} while (0)

#define TILE_STEP(fbp, wbp, kk) do { \
    const float* _fp = (fbp) + (kk) * FT_PITCH + tr * 8; \
    const float* _wp = (wbp) + (kk) * NCOL + tc * 8; \
    float4 f0 = *(const float4*)_fp; \
    float4 f1 = *(const float4*)(_fp + 4); \
    float4 w0 = *(const float4*)_wp; \
    float4 w1 = *(const float4*)(_wp + 4); \
    FMA8(a00, a01, f0.x); FMA8(a10, a11, f0.y); \
    FMA8(a20, a21, f0.z); FMA8(a30, a31, f0.w); \
    FMA8(a40, a41, f1.x); FMA8(a50, a51, f1.y); \
    FMA8(a60, a61, f1.z); FMA8(a70, a71, f1.w); \
} while (0)

#define STAGE_WRITE(fb, fq, q) do { \
    (fb)[(fk + 0) * FT_PITCH + fr + 64 * (q)] = fq.x; \
    (fb)[(fk + 1) * FT_PITCH + fr + 64 * (q)] = fq.y; \
    (fb)[(fk + 2) * FT_PITCH + fr + 64 * (q)] = fq.z; \
    (fb)[(fk + 3) * FT_PITCH + fr + 64 * (q)] = fq.w; \
} while (0)

#define ZEROACC() do { \
    a00.x=a00.y=a00.z=a00.w=0.f; a01.x=a01.y=a01.z=a01.w=0.f; \
    a10.x=a10.y=a10.z=a10.w=0.f; a11.x=a11.y=a11.z=a11.w=0.f; \
    a20.x=a20.y=a20.z=a20.w=0.f; a21.x=a21.y=a21.z=a21.w=0.f; \
    a30.x=a30.y=a30.z=a30.w=0.f; a31.x=a31.y=a31.z=a31.w=0.f; \
    a40.x=a40.y=a40.z=a40.w=0.f; a41.x=a41.y=a41.z=a41.w=0.f; \
    a50.x=a50.y=a50.z=a50.w=0.f; a51.x=a51.y=a51.z=a51.w=0.f; \
    a60.x=a60.y=a60.z=a60.w=0.f; a61.x=a61.y=a61.z=a61.w=0.f; \
    a70.x=a70.y=a70.z=a70.w=0.f; a71.x=a71.y=a71.z=a71.w=0.f; \
} while (0)

__global__ __launch_bounds__(THREADS, 2)
void mps_fused(const float* __restrict__ feat, const float* __restrict__ encW,
               const float* __restrict__ encB, const float* __restrict__ lng,
               const float* __restrict__ lnb,  const float* __restrict__ mf,
               const float* __restrict__ W1,   const float* __restrict__ b1,
               const float* __restrict__ W2,   const float* __restrict__ b2,
               float* __restrict__ out)
{
    __shared__ float smem[SMEM_FLOATS];
    const int t  = threadIdx.x;
    const int tr = t >> 3;          // 0..31 : row-group (8 rows each)
    const int tc = t & 7;           // 0..7  : col-group (8 cols each)
    const long r0 = (long)blockIdx.x * BM;

    float4 a00, a01, a10, a11, a20, a21, a30, a31;
    float4 a40, a41, a50, a51, a60, a61, a70, a71;
    ZEROACC();

    // staging roles
    const int fr = t >> 2;          // 0..63 feature row within quarter
    const int fk = (t & 3) * 4;     // 0,4,8,12 : k offset (float4)
    const int wk = t >> 4;          // 0..15 W k row
    const int wc = (t & 15) * 4;    // 0..60 W col (float4)

    // ---------------- prologue: stage k-step 0 ----------------
    {
        float4 fA = *(const float4*)(feat + (r0 + fr +   0) * KTOT + fk);
        float4 fB = *(const float4*)(feat + (r0 + fr +  64) * KTOT + fk);
        float4 fC = *(const float4*)(feat + (r0 + fr + 128) * KTOT + fk);
        float4 fD = *(const float4*)(feat + (r0 + fr + 192) * KTOT + fk);
        float4 wv4 = *(const float4*)(encW + (long)wk * NCOL + wc);
        float* fb = smem;
        STAGE_WRITE(fb, fA, 0); STAGE_WRITE(fb, fB, 1);
        STAGE_WRITE(fb, fC, 2); STAGE_WRITE(fb, fD, 3);
        *(float4*)(smem + WT_OFF + wk * NCOL + wc) = wv4;
    }
    __syncthreads();

    // ---------------- K loop: double-buffered ----------------
    for (int s = 0; s < NSTEP; ++s) {
        float4 fA, fB, fC, fD, wv4;
        if (s + 1 < NSTEP) {
            const int k0 = (s + 1) * KT;
            fA = *(const float4*)(feat + (r0 + fr +   0) * KTOT + k0 + fk);
            fB = *(const float4*)(feat + (r0 + fr +  64) * KTOT + k0 + fk);
            fC = *(const float4*)(feat + (r0 + fr + 128) * KTOT + k0 + fk);
            fD = *(const float4*)(feat + (r0 + fr + 192) * KTOT + k0 + fk);
            wv4 = *(const float4*)(encW + (long)(k0 + wk) * NCOL + wc);
        }
        const float* fb = smem + (s & 1) * FT_BUF;
        const float* wb = smem + WT_OFF + (s & 1) * WT_BUF;
        #pragma unroll
        for (int kk = 0; kk < KT; ++kk) TILE_STEP(fb, wb, kk);
        if (s + 1 < NSTEP) {
            float* fbn = smem + ((s + 1) & 1) * FT_BUF;
            STAGE_WRITE(fbn, fA, 0); STAGE_WRITE(fbn, fB, 1);
            STAGE_WRITE(fbn, fC, 2); STAGE_WRITE(fbn, fD, 3);
            *(float4*)(smem + WT_OFF + ((s + 1) & 1) * WT_BUF + wk * NCOL + wc) = wv4;
        }
        __syncthreads();
    }

    // ---------------- bias + relu + LayerNorm stats (named scalars) ----------------
    float4 e0 = *(const float4*)(encB + tc * 8);
    float4 e1 = *(const float4*)(encB + tc * 8 + 4);

    #define BRELU(a0, a1, SS, QQ) \
        a0.x = fmaxf(a0.x + e0.x, 0.f); a0.y = fmaxf(a0.y + e0.y, 0.f); \
        a0.z = fmaxf(a0.z + e0.z, 0.f); a0.w = fmaxf(a0.w + e0.w, 0.f); \
        a1.x = fmaxf(a1.x + e1.x, 0.f); a1.y = fmaxf(a1.y + e1.y, 0.f); \
        a1.z = fmaxf(a1.z + e1.z, 0.f); a1.w = fmaxf(a1.w + e1.w, 0.f); \
        float SS = a0.x + a0.y + a0.z + a0.w + a1.x + a1.y + a1.z + a1.w; \
        float QQ = fmaf(a0.x, a0.x, fmaf(a0.y, a0.y, fmaf(a0.z, a0.z, fmaf(a0.w, a0.w, \
                   fmaf(a1.x, a1.x, fmaf(a1.y, a1.y, fmaf(a1.z, a1.z, a1.w * a1.w)))))));

    BRELU(a00, a01, s_0, q_0)  BRELU(a10, a11, s_1, q_1)
    BRELU(a20, a21, s_2, q_2)  BRELU(a30, a31, s_3, q_3)
    BRELU(a40, a41, s_4, q_4)  BRELU(a50, a51, s_5, q_5)
    BRELU(a60, a61, s_6, q_6)  BRELU(a70, a71, s_7, q_7)

    #define RED8(x) x += __shfl_xor(x, 1, 64); x += __shfl_xor(x, 2, 64); x += __shfl_xor(x, 4, 64);
    RED8(s_0) RED8(q_0) RED8(s_1) RED8(q_1) RED8(s_2) RED8(q_2) RED8(s_3) RED8(q_3)
    RED8(s_4) RED8(q_4) RED8(s_5) RED8(q_5) RED8(s_6) RED8(q_6) RED8(s_7) RED8(q_7)

    if (tc == 0) {
        float4 g4 = *(const float4*)lng;
        float4 b4 = *(const float4*)lnb;
        #define LNST(i, a0, SS, QQ) { \
            float mu  = SS * 0.015625f; \
            float var = QQ * 0.015625f - mu * mu; \
            float rs  = rsqrtf(var + 1e-5f); \
            float4 e; \
            e.x = (a0.x - mu) * rs * g4.x + b4.x; \
            e.y = (a0.y - mu) * rs * g4.y + b4.y; \
            e.z = (a0.z - mu) * rs * g4.z + b4.z; \
            e.w = (a0.w - mu) * rs * g4.w + b4.w; \
            *(float4*)(smem + ENC0_OFF + (tr * 8 + (i)) * 4) = e; }
        LNST(0, a00, s_0, q_0) LNST(1, a10, s_1, q_1)
        LNST(2, a20, s_2, q_2) LNST(3, a30, s_3, q_3)
        LNST(4, a40, s_4, q_4) LNST(5, a50, s_5, q_5)
        LNST(6, a60, s_6, q_6) LNST(7, a70, s_7, q_7)
    }

    // overlay epilogue weights into the (now dead) wt region
    for (int idx = t; idx < 128; idx += THREADS)  smem[MF_OFF + idx] = mf[idx];
    for (int idx = t; idx < 2048; idx += THREADS) smem[W1_OFF + idx] = W1[idx];
    if (t < 64)                    smem[B1_OFF + t]        = b1[t];
    else if (t < 128)              smem[W2_OFF + (t - 64)] = W2[t - 64];
    else if (t == 128)             smem[B2_OFF]            = b2[0];
    __syncthreads();

    // ---------------- MPS site-0: cs^T[32][256] into LDS (no arrays) ----------------
    {
        float4 e = *(const float4*)(smem + ENC0_OFF + t * 4);
        #pragma unroll
        for (int xq = 0; xq < 8; ++xq) {
            float4 m0 = *(const float4*)(smem + MF_OFF +  0 + xq * 4);
            float4 m1 = *(const float4*)(smem + MF_OFF + 32 + xq * 4);
            float4 m2 = *(const float4*)(smem + MF_OFF + 64 + xq * 4);
            float4 m3 = *(const float4*)(smem + MF_OFF + 96 + xq * 4);
            float c0 = fmaf(e.x, m0.x, fmaf(e.y, m1.x, fmaf(e.z, m2.x, e.w * m3.x)));
            float c1 = fmaf(e.x, m0.y, fmaf(e.y, m1.y, fmaf(e.z, m2.y, e.w * m3.y)));
            float c2 = fmaf(e.x, m0.z, fmaf(e.y, m1.z, fmaf(e.z, m2.z, e.w * m3.z)));
            float c3 = fmaf(e.x, m0.w, fmaf(e.y, m1.w, fmaf(e.z, m2.w, e.w * m3.w)));
            smem[CS_OFF + (xq * 4 + 0) * CS_PITCH + t] = c0;
            smem[CS_OFF + (xq * 4 + 1) * CS_PITCH + t] = c1;
            smem[CS_OFF + (xq * 4 + 2) * CS_PITCH + t] = c2;
            smem[CS_OFF + (xq * 4 + 3) * CS_PITCH + t] = c3;
        }
    }
    __syncthreads();

    // ---------------- decoder GEMM: C2[256][64] = cs^T' @ W1 ----------------
    ZEROACC();
    #pragma unroll 4
    for (int kk = 0; kk < 32; ++kk)
        TILE_STEP(smem + CS_OFF, smem + W1_OFF, kk);   // CS_PITCH == FT_PITCH, W1 pitch == NCOL

    // ---------------- bias + relu + dot(W2) + 8-lane reduce + sigmoid ----------------
    {
        float4 bb0 = *(const float4*)(smem + B1_OFF + tc * 8);
        float4 bb1 = *(const float4*)(smem + B1_OFF + tc * 8 + 4);
        float4 ww0 = *(const float4*)(smem + W2_OFF + tc * 8);
        float4 ww1 = *(const float4*)(smem + W2_OFF + tc * 8 + 4);
        const float b2v = smem[B2_OFF];
        #define OUTROW(i, a0, a1) { \
            float z = fmaxf(a0.x + bb0.x, 0.f) * ww0.x; \
            z = fmaf(fmaxf(a0.y + bb0.y, 0.f), ww0.y, z); \
            z = fmaf(fmaxf(a0.z + bb0.z, 0.f), ww0.z, z); \
            z = fmaf(fmaxf(a0.w + bb0.w, 0.f), ww0.w, z); \
            z = fmaf(fmaxf(a1.x + bb1.x, 0.f), ww1.x, z); \
            z = fmaf(fmaxf(a1.y + bb1.y, 0.f), ww1.y, z); \
            z = fmaf(fmaxf(a1.z + bb1.z, 0.f), ww1.z, z); \
            z = fmaf(fmaxf(a1.w + bb1.w, 0.f), ww1.w, z); \
            z += __shfl_xor(z, 1, 64); z += __shfl_xor(z, 2, 64); z += __shfl_xor(z, 4, 64); \
            if (tc == 0) out[r0 + tr * 8 + (i)] = 1.f / (1.f + expf(-(z + b2v))); }
        OUTROW(0, a00, a01) OUTROW(1, a10, a11)
        OUTROW(2, a20, a21) OUTROW(3, a30, a31)
        OUTROW(4, a40, a41) OUTROW(5, a50, a51)
        OUTROW(6, a60, a61) OUTROW(7, a70, a71)
    }
}

extern "C" void kernel_launch(void* const* d_in, const int* in_sizes, int n_in,
                              void* d_out, int out_size, void* d_ws, size_t ws_size,
                              hipStream_t stream)
{
    const float* feat = (const float*)d_in[0];   // [B,512]
    const float* encW = (const float*)d_in[1];   // [512,64]
    const float* encB = (const float*)d_in[2];   // [64]
    const float* lng  = (const float*)d_in[3];   // [64] (only 0..3 used)
    const float* lnb  = (const float*)d_in[4];   // [64] (only 0..3 used)
    const float* mf   = (const float*)d_in[5];   // [4,32]
    // d_in[6] = mps_mid, d_in[7] = mps_last : dead code in the reference
    const float* W1   = (const float*)d_in[8];   // [32,64]
    const float* b1   = (const float*)d_in[9];   // [64]
    const float* W2   = (const float*)d_in[10];  // [64,1]
    const float* b2   = (const float*)d_in[11];  // [1]
    float* out = (float*)d_out;

    dim3 grid(BATCH / BM), block(THREADS);
    hipLaunchKernelGGL(mps_fused, grid, block, 0, stream,
                       feat, encW, encB, lng, lnb, mf, W1, b1, W2, b2, out);
}